// Round 1
// baseline (314.072 us; speedup 1.0000x reference)
//
#include <hip/hip_runtime.h>
#include <hip/hip_bf16.h>
#include <cstdint>
#include <cstddef>

#define BSZ 8
#define NN 2048
#define HH 512
#define MROWS (BSZ * NN)   // 16384
#define LOG2E 1.44269504088896f

typedef __attribute__((ext_vector_type(4))) float f32x4;
typedef __attribute__((ext_vector_type(8))) short short8;
typedef __attribute__((ext_vector_type(4))) unsigned short us4;
typedef __attribute__((ext_vector_type(4))) uint32_t u32x4;

#if __has_builtin(__builtin_amdgcn_exp2f)
#define EXP2(x) __builtin_amdgcn_exp2f(x)
#else
#define EXP2(x) __expf((x) * 0.69314718056f)
#endif

static __device__ __forceinline__ unsigned short f2bf(float f) {
    uint32_t u = __builtin_bit_cast(uint32_t, f);
    u += 0x7fffu + ((u >> 16) & 1u);
    return (unsigned short)(u >> 16);
}

static __device__ __forceinline__ void async16(const unsigned short* g, unsigned short* l) {
    __builtin_amdgcn_global_load_lds(
        (const __attribute__((address_space(1))) void*)g,
        (__attribute__((address_space(3))) void*)l, 16, 0, 0);
}

// =====================================================================================
// K0 prep: blocks [0,2048): feats -> bf16 (4 f32x4/thread)
//          blocks [2048,2112): fc_w -> bf16
//          blocks [2112,4160): adj -> bitmask  (moved out of k2: pure BW streaming)
// =====================================================================================
__global__ __launch_bounds__(256) void prep_kernel(
    const float* __restrict__ feats, const float* __restrict__ fc_w,
    const float* __restrict__ adj,
    unsigned short* __restrict__ feats_bf, unsigned short* __restrict__ fcw_bf,
    unsigned char* __restrict__ maskb) {
    const int bid = blockIdx.x;
    const int tid = threadIdx.x;
    if (bid < 2048) {
        const int base = bid * 1024 + tid;
#pragma unroll
        for (int j = 0; j < 4; ++j) {
            const int i = base + j * 256;
            f32x4 v = ((const f32x4*)feats)[i];
            us4 o;
#pragma unroll
            for (int c = 0; c < 4; ++c) o[c] = f2bf(v[c]);
            ((us4*)feats_bf)[i] = o;
        }
    } else if (bid < 2112) {
        const int base = (bid - 2048) * 1024 + tid;
#pragma unroll
        for (int j = 0; j < 4; ++j) {
            const int i = base + j * 256;
            f32x4 v = ((const f32x4*)fc_w)[i];
            us4 o;
#pragma unroll
            for (int c = 0; c < 4; ++c) o[c] = f2bf(v[c]);
            ((us4*)fcw_bf)[i] = o;
        }
    } else {
        // ---- adj -> bitmask: 8 rows per block ----
        const int a = bid - 2112;            // 0..2047
        const int wave = tid >> 6, lane = tid & 63;
#pragma unroll
        for (int s = 0; s < 2; ++s) {
            const int row = a * 8 + s * 4 + wave;
            const float* ar = adj + (size_t)row * NN;
#pragma unroll
            for (int p = 0; p < 4; ++p) {
                f32x4 v0 = *(const f32x4*)&ar[p * 512 + lane * 8];
                f32x4 v1 = *(const f32x4*)&ar[p * 512 + lane * 8 + 4];
                float fb = v0[0] + 2.f * v0[1] + 4.f * v0[2] + 8.f * v0[3]
                         + 16.f * v1[0] + 32.f * v1[1] + 64.f * v1[2] + 128.f * v1[3];
                maskb[(size_t)row * 256 + p * 64 + lane] = (unsigned char)(unsigned int)fb;
            }
        }
    }
}

// =====================================================================================
// K2: pure gemm_fp (feat_proj) via async16 bf16 staging, now DOUBLE-BUFFERED:
//     stage next K-tile BEFORE computing current one; one barrier per K-step.
//     + q/k partials epilogue (unchanged).
// =====================================================================================
__global__ __launch_bounds__(256) void k2_kernel(
    const unsigned short* __restrict__ A, const unsigned short* __restrict__ Bt,
    const float* __restrict__ fc_b, const float* __restrict__ q_w,
    const float* __restrict__ k_w,
    unsigned short* __restrict__ fpT,
    float* __restrict__ qpart, float* __restrict__ kpart) {
    __shared__ alignas(16) unsigned short As[2][128 * 32];   // 16 KB
    __shared__ alignas(16) unsigned short Bs[2][128 * 32];   // 16 KB
    __shared__ float qred[2][128], kred[2][128];
    const int bid = blockIdx.x;
    const int tid = threadIdx.x;
    const int wave = tid >> 6, lane = tid & 63;
    const int wi = wave >> 1, wj = wave & 1;
    const int n0 = (bid & 3) * 128;     // o tile
    const int i0 = (bid >> 2) * 128;    // flat row tile
    const int K = HH;
    const int lrow = lane >> 2;         // 0..15
    const int lseg = (lane & 3) * 8;    // 0,8,16,24
    const int fro = (lane & 15) * 32 + (lane >> 4) * 8;
    f32x4 acc[4][4];
#pragma unroll
    for (int a = 0; a < 4; ++a)
#pragma unroll
        for (int c = 0; c < 4; ++c) acc[a][c] = (f32x4)(0.f);

    auto stage = [&](int buf, int k0) {
        const int c0 = wave * 2;
        const unsigned short* ga = A + (size_t)(i0 + c0 * 16 + lrow) * K + k0 + lseg;
        async16(ga, &As[buf][(c0 * 16) * 32]);
        async16(ga + (size_t)16 * K, &As[buf][(c0 * 16 + 16) * 32]);
        const unsigned short* gb = Bt + (size_t)(n0 + c0 * 16 + lrow) * K + k0 + lseg;
        async16(gb, &Bs[buf][(c0 * 16) * 32]);
        async16(gb + (size_t)16 * K, &Bs[buf][(c0 * 16 + 16) * 32]);
    };

    // prologue: fill buffer 0
    stage(0, 0);
    __syncthreads();

    for (int k0 = 0; k0 < K; k0 += 32) {
        const int p = (k0 >> 5) & 1;
        if (k0 + 32 < K) stage(p ^ 1, k0 + 32);   // issue next tile's loads first
        short8 af[4], bf[4];
#pragma unroll
        for (int t = 0; t < 4; ++t) af[t] = *(const short8*)&As[p][(wi * 64 + t * 16) * 32 + fro];
#pragma unroll
        for (int t = 0; t < 4; ++t) bf[t] = *(const short8*)&Bs[p][(wj * 64 + t * 16) * 32 + fro];
#pragma unroll
        for (int it = 0; it < 4; ++it)
#pragma unroll
            for (int jt = 0; jt < 4; ++jt)
                acc[it][jt] = __builtin_amdgcn_mfma_f32_16x16x32_bf16(af[it], bf[jt], acc[it][jt], 0, 0, 0);
        __syncthreads();   // drains staging (vmcnt) + guards LDS reuse; 1 barrier/iter
    }

    int colv[4]; float cbv[4], qwv[4], kwv[4];
#pragma unroll
    for (int jt = 0; jt < 4; ++jt) {
        colv[jt] = n0 + wj * 64 + jt * 16 + (lane & 15);
        cbv[jt] = fc_b[colv[jt]];
        qwv[jt] = q_w[colv[jt]];
        kwv[jt] = k_w[colv[jt]];
    }
    const int b = i0 >> 11;
    const int il = i0 & 2047;
#pragma unroll
    for (int jt = 0; jt < 4; ++jt) {
#pragma unroll
        for (int it = 0; it < 4; ++it) {
            const int rb = wi * 64 + it * 16 + ((lane >> 4) << 2);
            us4 o;
#pragma unroll
            for (int r = 0; r < 4; ++r) o[r] = f2bf(acc[it][jt][r] + cbv[jt]);
            *(us4*)(fpT + ((size_t)b * HH + colv[jt]) * NN + il + rb) = o;
        }
    }
    // q/k partials over this block's 128 o-cols
#pragma unroll
    for (int it = 0; it < 4; ++it) {
#pragma unroll
        for (int r = 0; r < 4; ++r) {
            float pq = 0.f, pk = 0.f;
#pragma unroll
            for (int jt = 0; jt < 4; ++jt) {
                float v = acc[it][jt][r] + cbv[jt];
                pq += v * qwv[jt];
                pk += v * kwv[jt];
            }
            for (int off = 1; off < 16; off <<= 1) {
                pq += __shfl_xor(pq, off, 64);
                pk += __shfl_xor(pk, off, 64);
            }
            if ((lane & 15) == 0) {
                const int rr = wi * 64 + it * 16 + ((lane >> 4) << 2) + r;
                qred[wj][rr] = pq;
                kred[wj][rr] = pk;
            }
        }
    }
    __syncthreads();
    if (tid < 128) {
        const size_t o = (size_t)(n0 >> 7) * MROWS + i0 + tid;
        qpart[o] = qred[0][tid] + qred[1][tid];
        kpart[o] = kred[0][tid] + kred[1][tid];
    }
}

// =====================================================================================
// K3 v3: fused W-build + PV GEMM, double-buffered (1 barrier/iter), Z via ones-MFMA.
// M=64 x N=256 per block, BK=32. Transform packs bf16 by truncation (perm only).
// =====================================================================================
__global__ __launch_bounds__(256) void fused_pv_kernel(
    const unsigned short* __restrict__ fpT, const unsigned char* __restrict__ maskb,
    const float* __restrict__ qpart, const float* __restrict__ kpart,
    const float* __restrict__ q_b, const float* __restrict__ k_b,
    const float* __restrict__ feats, float* __restrict__ out) {
    __shared__ alignas(16) unsigned short As[2][64 * 32];    // 8 KB
    __shared__ alignas(16) unsigned short Bs[2][256 * 32];   // 32 KB
    __shared__ float kLDS[NN];                               // 8 KB
    __shared__ float qLDS[64];
    __shared__ float rzl[64];
    const int tid = threadIdx.x;
    const int wave = tid >> 6, lane = tid & 63;
    const int wi = wave >> 1, wj = wave & 1;
    const int bid = blockIdx.x;
    const int b = bid & 7;               // batch == XCD slot for fpT L2 locality
    const int t6 = bid >> 3;             // 0..63
    const int i0 = (t6 >> 1) * 64;       // row tile within batch
    const int n0 = (t6 & 1) * 256;       // h half
    const size_t rowbase = (size_t)b * NN + i0;

    // prologue: prescaled k (all 2048) and q (64 rows) into LDS
    {
        const float kb = k_b[0], qb = q_b[0];
#pragma unroll
        for (int s = 0; s < 8; ++s) {
            const int j = s * 256 + tid;
            const size_t gj = (size_t)b * NN + j;
            kLDS[j] = (kpart[gj] + kpart[MROWS + gj] + kpart[2 * MROWS + gj]
                     + kpart[3 * MROWS + gj] + kb) * LOG2E;
        }
        if (tid < 64) {
            const size_t gi = rowbase + tid;
            qLDS[tid] = (qpart[gi] + qpart[MROWS + gi] + qpart[2 * MROWS + gi]
                       + qpart[3 * MROWS + gi] + qb) * LOG2E;
        }
    }
    __syncthreads();

    const int r0 = tid >> 2;            // 0..63: W row handled by this thread
    const int c8 = (tid & 3) * 8;       // 8 consecutive K cols
    const float qi = qLDS[r0];

    const unsigned short* Bt = fpT + (size_t)b * HH * NN;
    const uint32_t* mk = (const uint32_t*)maskb;
    const size_t mrow = (rowbase + r0) * 64;
    const int lrow = lane >> 2, lseg = (lane & 3) * 8;
    const int fro = (lane & 15) * 32 + (lane >> 4) * 8;

    auto stageB = [&](int buf, int k0) {
        const int rbase = wave * 64;
        const unsigned short* gb = Bt + (size_t)(n0 + rbase + lrow) * NN + k0 + lseg;
        async16(gb, &Bs[buf][rbase * 32]);
        async16(gb + (size_t)16 * NN, &Bs[buf][(rbase + 16) * 32]);
        async16(gb + (size_t)32 * NN, &Bs[buf][(rbase + 32) * 32]);
        async16(gb + (size_t)48 * NN, &Bs[buf][(rbase + 48) * 32]);
    };
    auto transform = [&](int buf, int k0, uint32_t mbits) {
        const f32x4 kv0 = *(const f32x4*)&kLDS[k0 + c8];
        const f32x4 kv1 = *(const f32x4*)&kLDS[k0 + c8 + 4];
        const uint32_t byte8 = (mbits >> c8) & 0xffu;
        float wv[8];
#pragma unroll
        for (int c = 0; c < 8; ++c) {
            float s = qi + (c < 4 ? kv0[c] : kv1[c - 4]);
            s = fmaxf(s, 0.01f * s);
            const float e = EXP2(s);
            wv[c] = ((byte8 >> c) & 1u) ? e : 0.f;
        }
        u32x4 pk;
#pragma unroll
        for (int p = 0; p < 4; ++p) {
            const uint32_t lo = __builtin_bit_cast(uint32_t, wv[2 * p]);
            const uint32_t hi = __builtin_bit_cast(uint32_t, wv[2 * p + 1]);
            pk[p] = __builtin_amdgcn_perm(hi, lo, 0x07060302u);  // truncate-pack 2x bf16
        }
        *(u32x4*)&As[buf][r0 * 32 + c8] = pk;  // byte addr = tid*16, linear, conflict-free
    };

    f32x4 acc[2][8];
#pragma unroll
    for (int a = 0; a < 2; ++a)
#pragma unroll
        for (int c = 0; c < 8; ++c) acc[a][c] = (f32x4)(0.f);
    f32x4 acc_z[2] = {(f32x4)(0.f), (f32x4)(0.f)};
    short8 ones;
#pragma unroll
    for (int j = 0; j < 8; ++j) ones[j] = (short)0x3F80;   // bf16 1.0

    // prologue: fill buffer 0, prefetch mask for k0=32
    stageB(0, 0);
    transform(0, 0, mk[mrow]);
    uint32_t mnext = mk[mrow + 1];
    __syncthreads();

    for (int k0 = 0; k0 < NN; k0 += 32) {
        const int p = (k0 >> 5) & 1;
        if (k0 + 32 < NN) {
            stageB(p ^ 1, k0 + 32);
            uint32_t mfar = 0;
            if (k0 + 64 < NN) mfar = mk[mrow + ((k0 + 64) >> 5)];
            transform(p ^ 1, k0 + 32, mnext);
            mnext = mfar;
        }
        short8 af[2], bf[8];
#pragma unroll
        for (int t = 0; t < 2; ++t) af[t] = *(const short8*)&As[p][(wi * 32 + t * 16) * 32 + fro];
#pragma unroll
        for (int t = 0; t < 8; ++t) bf[t] = *(const short8*)&Bs[p][(wj * 128 + t * 16) * 32 + fro];
#pragma unroll
        for (int it = 0; it < 2; ++it)
#pragma unroll
            for (int jt = 0; jt < 8; ++jt)
                acc[it][jt] = __builtin_amdgcn_mfma_f32_16x16x32_bf16(af[it], bf[jt], acc[it][jt], 0, 0, 0);
        if (wj == 0) {
#pragma unroll
            for (int it = 0; it < 2; ++it)
                acc_z[it] = __builtin_amdgcn_mfma_f32_16x16x32_bf16(af[it], ones, acc_z[it], 0, 0, 0);
        }
        __syncthreads();
    }

    // Z: wj==0 waves hold row sums in acc_z (all 16 cols identical)
    if (wj == 0 && (lane & 15) == 0) {
#pragma unroll
        for (int it = 0; it < 2; ++it) {
            const int rb = wi * 32 + it * 16 + ((lane >> 4) << 2);
#pragma unroll
            for (int r = 0; r < 4; ++r) rzl[rb + r] = 1.0f / acc_z[it][r];
        }
    }
    __syncthreads();

    // epilogue: scale by 1/Z, add residual, plain fp32 stores
#pragma unroll
    for (int it = 0; it < 2; ++it) {
        const int rb = wi * 32 + it * 16 + ((lane >> 4) << 2);
        float rv[4];
#pragma unroll
        for (int r = 0; r < 4; ++r) rv[r] = rzl[rb + r];
#pragma unroll
        for (int jt = 0; jt < 8; ++jt) {
            const int col = n0 + wj * 128 + jt * 16 + (lane & 15);
#pragma unroll
            for (int r = 0; r < 4; ++r) {
                const size_t idx = (rowbase + rb + r) * HH + col;
                out[idx] = acc[it][jt][r] * rv[r] + feats[idx];
            }
        }
    }
}

extern "C" void kernel_launch(void* const* d_in, const int* in_sizes, int n_in,
                              void* d_out, int out_size, void* d_ws, size_t ws_size,
                              hipStream_t stream) {
    const float* feats = (const float*)d_in[0];
    const float* adj   = (const float*)d_in[1];
    const float* fc_w  = (const float*)d_in[2];
    const float* fc_b  = (const float*)d_in[3];
    const float* q_w   = (const float*)d_in[4];
    const float* q_b   = (const float*)d_in[5];
    const float* k_w   = (const float*)d_in[6];
    const float* k_b   = (const float*)d_in[7];
    float* out = (float*)d_out;

    char* w = (char*)d_ws;
    auto alloc = [&](size_t bytes) {
        char* p = w;
        w += (bytes + 255) & ~(size_t)255;
        return p;
    };
    unsigned short* feats_bf = (unsigned short*)alloc((size_t)BSZ * NN * HH * 2); // 16.8 MB
    unsigned short* fcw_bf   = (unsigned short*)alloc((size_t)HH * HH * 2);       // 0.5 MB
    unsigned short* fpT   = (unsigned short*)alloc((size_t)BSZ * HH * NN * 2);    // 16.8 MB
    unsigned char*  maskb = (unsigned char*)alloc((size_t)MROWS * 256);           // 4.2 MB
    float* qpart = (float*)alloc((size_t)4 * MROWS * 4);                          // 256 KB
    float* kpart = (float*)alloc((size_t)4 * MROWS * 4);                          // 256 KB

    prep_kernel<<<4160, 256, 0, stream>>>(feats, fc_w, adj, feats_bf, fcw_bf, maskb);
    k2_kernel<<<512, 256, 0, stream>>>(feats_bf, fcw_bf, fc_b, q_w, k_w,
                                       fpT, qpart, kpart);
    fused_pv_kernel<<<512, 256, 0, stream>>>(
        fpT, maskb, qpart, kpart, q_b, k_b, feats, out);
}

// Round 2
// 304.350 us; speedup vs baseline: 1.0319x; 1.0319x over previous
//
#include <hip/hip_runtime.h>
#include <hip/hip_bf16.h>
#include <cstdint>
#include <cstddef>

#define BSZ 8
#define NN 2048
#define HH 512
#define MROWS (BSZ * NN)   // 16384
#define LOG2E 1.44269504088896f

typedef __attribute__((ext_vector_type(4))) float f32x4;
typedef __attribute__((ext_vector_type(8))) short short8;
typedef __attribute__((ext_vector_type(4))) unsigned short us4;
typedef __attribute__((ext_vector_type(4))) uint32_t u32x4;

#if __has_builtin(__builtin_amdgcn_exp2f)
#define EXP2(x) __builtin_amdgcn_exp2f(x)
#else
#define EXP2(x) __expf((x) * 0.69314718056f)
#endif

static __device__ __forceinline__ unsigned short f2bf(float f) {
    uint32_t u = __builtin_bit_cast(uint32_t, f);
    u += 0x7fffu + ((u >> 16) & 1u);
    return (unsigned short)(u >> 16);
}

static __device__ __forceinline__ void async16(const unsigned short* g, unsigned short* l) {
    __builtin_amdgcn_global_load_lds(
        (const __attribute__((address_space(1))) void*)g,
        (__attribute__((address_space(3))) void*)l, 16, 0, 0);
}

// =====================================================================================
// K0 prep: blocks [0,2048): feats -> bf16 ; blocks [2048,2112): fc_w -> bf16
// =====================================================================================
__global__ __launch_bounds__(256) void prep_kernel(
    const float* __restrict__ feats, const float* __restrict__ fc_w,
    unsigned short* __restrict__ feats_bf, unsigned short* __restrict__ fcw_bf) {
    const int bid = blockIdx.x;
    const int tid = threadIdx.x;
    if (bid < 2048) {
        const int base = bid * 1024 + tid;
#pragma unroll
        for (int j = 0; j < 4; ++j) {
            const int i = base + j * 256;
            f32x4 v = ((const f32x4*)feats)[i];
            us4 o;
#pragma unroll
            for (int c = 0; c < 4; ++c) o[c] = f2bf(v[c]);
            ((us4*)feats_bf)[i] = o;
        }
    } else {
        const int base = (bid - 2048) * 1024 + tid;
#pragma unroll
        for (int j = 0; j < 4; ++j) {
            const int i = base + j * 256;
            f32x4 v = ((const f32x4*)fc_w)[i];
            us4 o;
#pragma unroll
            for (int c = 0; c < 4; ++c) o[c] = f2bf(v[c]);
            ((us4*)fcw_bf)[i] = o;
        }
    }
}

// =====================================================================================
// K2: gemm_fp 64x128 tiles (1024 blocks, double-buffered, 1 barrier/K-step)
//     interleaved with adj->bitmask streaming blocks (2048) for BW/latency overlap.
//     bid%3==0 -> gemm block bid/3 ; else adj block.
// =====================================================================================
__global__ __launch_bounds__(256) void k2_kernel(
    const unsigned short* __restrict__ A, const unsigned short* __restrict__ Bt,
    const float* __restrict__ fc_b, const float* __restrict__ q_w,
    const float* __restrict__ k_w, const float* __restrict__ adj,
    unsigned short* __restrict__ fpT, unsigned char* __restrict__ maskb,
    float* __restrict__ qpart, float* __restrict__ kpart) {
    __shared__ alignas(16) unsigned short As[2][64 * 32];    // 8 KB
    __shared__ alignas(16) unsigned short Bs[2][128 * 32];   // 16 KB
    __shared__ float qred[2][64], kred[2][64];
    const int bid = blockIdx.x;
    const int tid = threadIdx.x;
    const int wave = tid >> 6, lane = tid & 63;
    if (bid % 3 == 0) {
        // ---------------- GEMM block ----------------
        const int g = bid / 3;              // 0..1023
        const int wi = wave >> 1, wj = wave & 1;
        const int n0 = (g & 3) * 128;       // o tile
        const int i0 = (g >> 2) * 64;       // flat row tile
        const int K = HH;
        const int lrow = lane >> 2;         // 0..15
        const int lseg = (lane & 3) * 8;    // 0,8,16,24
        const int fro = (lane & 15) * 32 + (lane >> 4) * 8;
        f32x4 acc[2][4];
#pragma unroll
        for (int a = 0; a < 2; ++a)
#pragma unroll
            for (int c = 0; c < 4; ++c) acc[a][c] = (f32x4)(0.f);

        auto stage = [&](int buf, int k0) {
            // A: 64 rows, each wave stages 16 (one async16)
            const unsigned short* ga = A + (size_t)(i0 + wave * 16 + lrow) * K + k0 + lseg;
            async16(ga, &As[buf][(wave * 16) * 32]);
            // B: 128 rows, each wave stages 32 (two async16)
            const unsigned short* gb = Bt + (size_t)(n0 + wave * 32 + lrow) * K + k0 + lseg;
            async16(gb, &Bs[buf][(wave * 32) * 32]);
            async16(gb + (size_t)16 * K, &Bs[buf][(wave * 32 + 16) * 32]);
        };

        stage(0, 0);
        __syncthreads();

        for (int k0 = 0; k0 < K; k0 += 32) {
            const int p = (k0 >> 5) & 1;
            if (k0 + 32 < K) stage(p ^ 1, k0 + 32);
            short8 af[2], bf[4];
#pragma unroll
            for (int t = 0; t < 2; ++t) af[t] = *(const short8*)&As[p][(wi * 32 + t * 16) * 32 + fro];
#pragma unroll
            for (int t = 0; t < 4; ++t) bf[t] = *(const short8*)&Bs[p][(wj * 64 + t * 16) * 32 + fro];
#pragma unroll
            for (int it = 0; it < 2; ++it)
#pragma unroll
                for (int jt = 0; jt < 4; ++jt)
                    acc[it][jt] = __builtin_amdgcn_mfma_f32_16x16x32_bf16(af[it], bf[jt], acc[it][jt], 0, 0, 0);
            __syncthreads();
        }

        int colv[4]; float cbv[4], qwv[4], kwv[4];
#pragma unroll
        for (int jt = 0; jt < 4; ++jt) {
            colv[jt] = n0 + wj * 64 + jt * 16 + (lane & 15);
            cbv[jt] = fc_b[colv[jt]];
            qwv[jt] = q_w[colv[jt]];
            kwv[jt] = k_w[colv[jt]];
        }
        const int b = i0 >> 11;
        const int il = i0 & 2047;
#pragma unroll
        for (int jt = 0; jt < 4; ++jt) {
#pragma unroll
            for (int it = 0; it < 2; ++it) {
                const int rb = wi * 32 + it * 16 + ((lane >> 4) << 2);
                us4 o;
#pragma unroll
                for (int r = 0; r < 4; ++r) o[r] = f2bf(acc[it][jt][r] + cbv[jt]);
                *(us4*)(fpT + ((size_t)b * HH + colv[jt]) * NN + il + rb) = o;
            }
        }
        // q/k partials over this block's 128 o-cols
#pragma unroll
        for (int it = 0; it < 2; ++it) {
#pragma unroll
            for (int r = 0; r < 4; ++r) {
                float pq = 0.f, pk = 0.f;
#pragma unroll
                for (int jt = 0; jt < 4; ++jt) {
                    float v = acc[it][jt][r] + cbv[jt];
                    pq += v * qwv[jt];
                    pk += v * kwv[jt];
                }
                for (int off = 1; off < 16; off <<= 1) {
                    pq += __shfl_xor(pq, off, 64);
                    pk += __shfl_xor(pk, off, 64);
                }
                if ((lane & 15) == 0) {
                    const int rr = wi * 32 + it * 16 + ((lane >> 4) << 2) + r;
                    qred[wj][rr] = pq;
                    kred[wj][rr] = pk;
                }
            }
        }
        __syncthreads();
        if (tid < 64) {
            const size_t o = (size_t)(n0 >> 7) * MROWS + i0 + tid;
            qpart[o] = qred[0][tid] + qred[1][tid];
            kpart[o] = kred[0][tid] + kred[1][tid];
        }
    } else {
        // ---------------- adj -> bitmask block (8 rows) ----------------
        const int a = (bid / 3) * 2 + (bid % 3) - 1;    // 0..2047
#pragma unroll
        for (int s = 0; s < 2; ++s) {
            const int row = a * 8 + s * 4 + wave;
            const float* ar = adj + (size_t)row * NN;
#pragma unroll
            for (int p = 0; p < 4; ++p) {
                f32x4 v0 = *(const f32x4*)&ar[p * 512 + lane * 8];
                f32x4 v1 = *(const f32x4*)&ar[p * 512 + lane * 8 + 4];
                float fb = v0[0] + 2.f * v0[1] + 4.f * v0[2] + 8.f * v0[3]
                         + 16.f * v1[0] + 32.f * v1[1] + 64.f * v1[2] + 128.f * v1[3];
                maskb[(size_t)row * 256 + p * 64 + lane] = (unsigned char)(unsigned int)fb;
            }
        }
    }
}

// =====================================================================================
// K3: fused W-build + PV GEMM. TRIPLE-buffered, counted vmcnt (loads stay in flight
// across raw s_barrier), T5 setprio around MFMA cluster. M=64 x N=256, BK=32.
// Per-iter j: [mask asm-load j+2][stage tile j+1 -> buf (j+1)%3][vmcnt(5)]
//             [transform tile j+1][lgkmcnt(0)][s_barrier][ds_read+MFMA tile j, buf j%3]
// vmcnt(5) retires exactly the prior iteration's {1 mask + 4 async16}.
// =====================================================================================
__global__ __launch_bounds__(256) void fused_pv_kernel(
    const unsigned short* __restrict__ fpT, const unsigned char* __restrict__ maskb,
    const float* __restrict__ qpart, const float* __restrict__ kpart,
    const float* __restrict__ q_b, const float* __restrict__ k_b,
    const float* __restrict__ feats, float* __restrict__ out) {
    __shared__ alignas(16) unsigned short As[3][64 * 32];    // 12 KB
    __shared__ alignas(16) unsigned short Bs[3][256 * 32];   // 48 KB
    __shared__ float kLDS[NN];                               // 8 KB
    __shared__ float qLDS[64];
    __shared__ float rzl[64];
    const int tid = threadIdx.x;
    const int wave = tid >> 6, lane = tid & 63;
    const int wi = wave >> 1, wj = wave & 1;
    const int bid = blockIdx.x;
    const int b = bid & 7;               // batch == XCD slot for fpT L2 locality
    const int t6 = bid >> 3;             // 0..63
    const int i0 = (t6 >> 1) * 64;       // row tile within batch
    const int n0 = (t6 & 1) * 256;       // h half
    const size_t rowbase = (size_t)b * NN + i0;

    // prologue: prescaled k (all 2048) and q (64 rows) into LDS
    {
        const float kb = k_b[0], qb = q_b[0];
#pragma unroll
        for (int s = 0; s < 8; ++s) {
            const int j = s * 256 + tid;
            const size_t gj = (size_t)b * NN + j;
            kLDS[j] = (kpart[gj] + kpart[MROWS + gj] + kpart[2 * MROWS + gj]
                     + kpart[3 * MROWS + gj] + kb) * LOG2E;
        }
        if (tid < 64) {
            const size_t gi = rowbase + tid;
            qLDS[tid] = (qpart[gi] + qpart[MROWS + gi] + qpart[2 * MROWS + gi]
                       + qpart[3 * MROWS + gi] + qb) * LOG2E;
        }
    }
    __syncthreads();

    const int r0 = tid >> 2;            // 0..63: W row handled by this thread
    const int c8 = (tid & 3) * 8;       // 8 consecutive K cols
    const float qi = qLDS[r0];

    const unsigned short* Bt = fpT + (size_t)b * HH * NN;
    const uint32_t* mk = (const uint32_t*)maskb;
    const size_t mrow = (rowbase + r0) * 64;
    const int lrow = lane >> 2, lseg = (lane & 3) * 8;
    const int fro = (lane & 15) * 32 + (lane >> 4) * 8;

    auto stageB = [&](int buf, int k0) {
        const int rbase = wave * 64;
        const unsigned short* gb = Bt + (size_t)(n0 + rbase + lrow) * NN + k0 + lseg;
        async16(gb, &Bs[buf][rbase * 32]);
        async16(gb + (size_t)16 * NN, &Bs[buf][(rbase + 16) * 32]);
        async16(gb + (size_t)32 * NN, &Bs[buf][(rbase + 32) * 32]);
        async16(gb + (size_t)48 * NN, &Bs[buf][(rbase + 48) * 32]);
    };
    auto transform = [&](int buf, int k0, uint32_t mbits) {
        const f32x4 kv0 = *(const f32x4*)&kLDS[k0 + c8];
        const f32x4 kv1 = *(const f32x4*)&kLDS[k0 + c8 + 4];
        const uint32_t byte8 = (mbits >> c8) & 0xffu;
        float wv[8];
#pragma unroll
        for (int c = 0; c < 8; ++c) {
            float s = qi + (c < 4 ? kv0[c] : kv1[c - 4]);
            s = fmaxf(s, 0.01f * s);
            const float e = EXP2(s);
            wv[c] = ((byte8 >> c) & 1u) ? e : 0.f;
        }
        u32x4 pk;
#pragma unroll
        for (int p = 0; p < 4; ++p) {
            const uint32_t lo = __builtin_bit_cast(uint32_t, wv[2 * p]);
            const uint32_t hi = __builtin_bit_cast(uint32_t, wv[2 * p + 1]);
            pk[p] = __builtin_amdgcn_perm(hi, lo, 0x07060302u);  // truncate-pack 2x bf16
        }
        *(u32x4*)&As[buf][r0 * 32 + c8] = pk;  // byte addr = tid*16, linear, conflict-free
    };

    f32x4 acc[2][8];
#pragma unroll
    for (int a = 0; a < 2; ++a)
#pragma unroll
        for (int c = 0; c < 8; ++c) acc[a][c] = (f32x4)(0.f);
    f32x4 acc_z[2] = {(f32x4)(0.f), (f32x4)(0.f)};
    short8 ones;
#pragma unroll
    for (int j = 0; j < 8; ++j) ones[j] = (short)0x3F80;   // bf16 1.0

    auto compute = [&](int rd) {
        short8 af[2], bf[8];
#pragma unroll
        for (int t = 0; t < 2; ++t) af[t] = *(const short8*)&As[rd][(wi * 32 + t * 16) * 32 + fro];
#pragma unroll
        for (int t = 0; t < 8; ++t) bf[t] = *(const short8*)&Bs[rd][(wj * 128 + t * 16) * 32 + fro];
        __builtin_amdgcn_s_setprio(1);
#pragma unroll
        for (int it = 0; it < 2; ++it)
#pragma unroll
            for (int jt = 0; jt < 8; ++jt)
                acc[it][jt] = __builtin_amdgcn_mfma_f32_16x16x32_bf16(af[it], bf[jt], acc[it][jt], 0, 0, 0);
        if (wj == 0) {
#pragma unroll
            for (int it = 0; it < 2; ++it)
                acc_z[it] = __builtin_amdgcn_mfma_f32_16x16x32_bf16(af[it], ones, acc_z[it], 0, 0, 0);
        }
        __builtin_amdgcn_s_setprio(0);
    };

    // ---- pipeline prologue: tile 0 into buf 0, drain, one raw barrier ----
    uint32_t mw_cur = mk[mrow];          // word 0 (compiler-managed wait, prologue only)
    uint32_t mw_nxt = mk[mrow + 1];      // word 1
    stageB(0, 0);
    transform(0, 0, mw_cur);
    asm volatile("s_waitcnt vmcnt(0)" ::: "memory");
    __builtin_amdgcn_sched_barrier(0);
    asm volatile("s_waitcnt lgkmcnt(0)" ::: "memory");
    __builtin_amdgcn_s_barrier();
    __builtin_amdgcn_sched_barrier(0);
    // entering loop with 0 outstanding VMEM

    // ---- main loop: j = 0..61 (steady state) ----
    for (int j = 0; j < 62; ++j) {
        const int k0 = j * 32;
        const int rd = j % 3, st = (j + 1) % 3;
        uint32_t mnn;
        {
            const uint32_t* ma = mk + mrow + j + 2;   // mask word j+2 (for tile j+2)
            asm volatile("global_load_dword %0, %1, off"
                         : "=v"(mnn) : "v"(ma) : "memory");
        }
        stageB(st, k0 + 32);                          // 4 async16 into buf st
        asm volatile("s_waitcnt vmcnt(5)" ::: "memory");   // prior iter's {mask,4 stages} done
        __builtin_amdgcn_sched_barrier(0);
        transform(st, k0 + 32, mw_nxt);               // uses mask word j+1 (retired above)
        mw_nxt = mnn;
        asm volatile("s_waitcnt lgkmcnt(0)" ::: "memory");
        __builtin_amdgcn_sched_barrier(0);
        __builtin_amdgcn_s_barrier();
        __builtin_amdgcn_sched_barrier(0);
        compute(rd);
    }
    // ---- j = 62: stage last tile (63), no mask load ----
    {
        const int k0 = 62 * 32;
        stageB(0, k0 + 32);                           // tile 63 -> buf 0
        asm volatile("s_waitcnt vmcnt(4)" ::: "memory");   // iter-61 {mask,4 stages} done
        __builtin_amdgcn_sched_barrier(0);
        transform(0, k0 + 32, mw_nxt);                // mask word 63
        asm volatile("s_waitcnt lgkmcnt(0)" ::: "memory");
        __builtin_amdgcn_sched_barrier(0);
        __builtin_amdgcn_s_barrier();
        __builtin_amdgcn_sched_barrier(0);
        compute(62 % 3);                              // buf 2
    }
    // ---- j = 63: drain and compute final tile ----
    {
        asm volatile("s_waitcnt vmcnt(0)" ::: "memory");
        __builtin_amdgcn_sched_barrier(0);
        asm volatile("s_waitcnt lgkmcnt(0)" ::: "memory");
        __builtin_amdgcn_s_barrier();
        __builtin_amdgcn_sched_barrier(0);
        compute(0);                                   // tile 63 in buf 0
    }

    // Z: wj==0 waves hold row sums in acc_z (all 16 cols identical)
    if (wj == 0 && (lane & 15) == 0) {
#pragma unroll
        for (int it = 0; it < 2; ++it) {
            const int rb = wi * 32 + it * 16 + ((lane >> 4) << 2);
#pragma unroll
            for (int r = 0; r < 4; ++r) rzl[rb + r] = 1.0f / acc_z[it][r];
        }
    }
    __syncthreads();

    // epilogue: scale by 1/Z, add residual, plain fp32 stores
#pragma unroll
    for (int it = 0; it < 2; ++it) {
        const int rb = wi * 32 + it * 16 + ((lane >> 4) << 2);
        float rv[4];
#pragma unroll
        for (int r = 0; r < 4; ++r) rv[r] = rzl[rb + r];
#pragma unroll
        for (int jt = 0; jt < 8; ++jt) {
            const int col = n0 + wj * 128 + jt * 16 + (lane & 15);
#pragma unroll
            for (int r = 0; r < 4; ++r) {
                const size_t idx = (rowbase + rb + r) * HH + col;
                out[idx] = acc[it][jt][r] * rv[r] + feats[idx];
            }
        }
    }
}

extern "C" void kernel_launch(void* const* d_in, const int* in_sizes, int n_in,
                              void* d_out, int out_size, void* d_ws, size_t ws_size,
                              hipStream_t stream) {
    const float* feats = (const float*)d_in[0];
    const float* adj   = (const float*)d_in[1];
    const float* fc_w  = (const float*)d_in[2];
    const float* fc_b  = (const float*)d_in[3];
    const float* q_w   = (const float*)d_in[4];
    const float* q_b   = (const float*)d_in[5];
    const float* k_w   = (const float*)d_in[6];
    const float* k_b   = (const float*)d_in[7];
    float* out = (float*)d_out;

    char* w = (char*)d_ws;
    auto alloc = [&](size_t bytes) {
        char* p = w;
        w += (bytes + 255) & ~(size_t)255;
        return p;
    };
    unsigned short* feats_bf = (unsigned short*)alloc((size_t)BSZ * NN * HH * 2); // 16.8 MB
    unsigned short* fcw_bf   = (unsigned short*)alloc((size_t)HH * HH * 2);       // 0.5 MB
    unsigned short* fpT   = (unsigned short*)alloc((size_t)BSZ * HH * NN * 2);    // 16.8 MB
    unsigned char*  maskb = (unsigned char*)alloc((size_t)MROWS * 256);           // 4.2 MB
    float* qpart = (float*)alloc((size_t)4 * MROWS * 4);                          // 256 KB
    float* kpart = (float*)alloc((size_t)4 * MROWS * 4);                          // 256 KB

    prep_kernel<<<2112, 256, 0, stream>>>(feats, fc_w, feats_bf, fcw_bf);
    k2_kernel<<<3072, 256, 0, stream>>>(feats_bf, fcw_bf, fc_b, q_w, k_w, adj,
                                        fpT, maskb, qpart, kpart);
    fused_pv_kernel<<<512, 256, 0, stream>>>(
        fpT, maskb, qpart, kpart, q_b, k_b, feats, out);
}